// Round 1
// baseline (199.723 us; speedup 1.0000x reference)
//
#include <hip/hip_runtime.h>
#include <math.h>

// Problem constants
#define B   64
#define LP  256
#define LH  384
#define D   512
#define CH  32      // rows per gather chunk

// ---------------------------------------------------------------------------
// K1: gather + sum embedding rows.
// grid = (8 + 12, 64): blockIdx.x < 8 -> pre chunks, else hyp chunks.
// block = 512 threads (one per column d). atomicAdd partial sums into S.
// ---------------------------------------------------------------------------
__global__ __launch_bounds__(512)
void gather_sum_kernel(const int* __restrict__ idx_pre,
                       const int* __restrict__ idx_hyp,
                       const float* __restrict__ emb,
                       float* __restrict__ Sp,
                       float* __restrict__ Sh) {
    const int b = blockIdx.y;
    int c = blockIdx.x;
    const int d = threadIdx.x;

    const int* idx;
    float* S;
    if (c < LP / CH) {
        idx = idx_pre + b * LP;
        S = Sp;
    } else {
        idx = idx_hyp + b * LH;
        S = Sh;
        c -= LP / CH;
    }

    __shared__ int sidx[CH];
    if (threadIdx.x < CH) sidx[threadIdx.x] = idx[c * CH + threadIdx.x];
    __syncthreads();

    float a0 = 0.f, a1 = 0.f, a2 = 0.f, a3 = 0.f;
#pragma unroll
    for (int r = 0; r < CH; r += 4) {
        a0 += emb[(size_t)sidx[r    ] * D + d];
        a1 += emb[(size_t)sidx[r + 1] * D + d];
        a2 += emb[(size_t)sidx[r + 2] * D + d];
        a3 += emb[(size_t)sidx[r + 3] * D + d];
    }
    atomicAdd(&S[b * D + d], (a0 + a1) + (a2 + a3));
}

// ---------------------------------------------------------------------------
// K2: h = relu(x @ W1 + b1), where x = [S_pre, S_hyp, S_hyp, S_pre].
// Folded: h[b,j] = relu(b1[j] + sum_d Sp[b,d]*(W1[d,j]+W1[1536+d,j])
//                              + Sh[b,d]*(W1[512+d,j]+W1[1024+d,j]))
// grid = (8 jb, 16 bb), block = 256 (64 j-lanes x 4 d-quarters).
// Each block: 4 batches x 64 output columns, full d range.
// ---------------------------------------------------------------------------
__global__ __launch_bounds__(256)
void mlp1_kernel(const float* __restrict__ Sp,
                 const float* __restrict__ Sh,
                 const float* __restrict__ W1,
                 const float* __restrict__ b1,
                 float* __restrict__ H) {
    const int jj = threadIdx.x & 63;
    const int dq = threadIdx.x >> 6;          // 0..3
    const int j  = blockIdx.x * 64 + jj;
    const int b0 = blockIdx.y * 4;

    __shared__ float sp[4][D];
    __shared__ float sh[4][D];
    for (int i = threadIdx.x; i < 4 * D; i += 256) {
        const int bb = i >> 9;
        const int dd = i & (D - 1);
        sp[bb][dd] = Sp[(b0 + bb) * D + dd];
        sh[bb][dd] = Sh[(b0 + bb) * D + dd];
    }
    __syncthreads();

    float acc0 = 0.f, acc1 = 0.f, acc2 = 0.f, acc3 = 0.f;
    const int d0 = dq * 128;
    for (int d = d0; d < d0 + 128; ++d) {
        const float wa = W1[(size_t)d * D + j] + W1[(size_t)(3 * D + d) * D + j];
        const float wb = W1[(size_t)(D + d) * D + j] + W1[(size_t)(2 * D + d) * D + j];
        acc0 += sp[0][d] * wa + sh[0][d] * wb;
        acc1 += sp[1][d] * wa + sh[1][d] * wb;
        acc2 += sp[2][d] * wa + sh[2][d] * wb;
        acc3 += sp[3][d] * wa + sh[3][d] * wb;
    }

    __shared__ float red[4][4][64];           // [dq][bb][jj]
    red[dq][0][jj] = acc0;
    red[dq][1][jj] = acc1;
    red[dq][2][jj] = acc2;
    red[dq][3][jj] = acc3;
    __syncthreads();

    // 256 threads -> 4 bb x 64 jj outputs
    const int bb = threadIdx.x >> 6;
    const float s = red[0][bb][jj] + red[1][bb][jj] + red[2][bb][jj] + red[3][bb][jj]
                  + b1[j];
    H[(size_t)(b0 + bb) * D + j] = s > 0.f ? s : 0.f;
}

// ---------------------------------------------------------------------------
// K3: out[b] = sigmoid(h[b,:] . W2 + b2). grid = 64, block = 256.
// ---------------------------------------------------------------------------
__global__ __launch_bounds__(256)
void mlp2_kernel(const float* __restrict__ H,
                 const float* __restrict__ W2,
                 const float* __restrict__ b2,
                 float* __restrict__ out) {
    const int b = blockIdx.x;
    const int t = threadIdx.x;

    float v = H[(size_t)b * D + t] * W2[t]
            + H[(size_t)b * D + 256 + t] * W2[256 + t];

    // wave-64 reduction
#pragma unroll
    for (int off = 32; off > 0; off >>= 1) v += __shfl_down(v, off);

    __shared__ float part[4];
    if ((t & 63) == 0) part[t >> 6] = v;
    __syncthreads();
    if (t == 0) {
        const float s = part[0] + part[1] + part[2] + part[3] + b2[0];
        out[b] = 1.f / (1.f + expf(-s));
    }
}

extern "C" void kernel_launch(void* const* d_in, const int* in_sizes, int n_in,
                              void* d_out, int out_size, void* d_ws, size_t ws_size,
                              hipStream_t stream) {
    const int*   inputs_pre = (const int*)d_in[0];
    const int*   inputs_hyp = (const int*)d_in[1];
    // d_in[2], d_in[3]: masks of ones -> unused (truncation is a no-op)
    const float* emb = (const float*)d_in[4];
    const float* W1  = (const float*)d_in[5];
    const float* b1  = (const float*)d_in[6];
    const float* W2  = (const float*)d_in[7];
    const float* b2  = (const float*)d_in[8];
    float* out = (float*)d_out;

    float* Sp = (float*)d_ws;            // [B, D]
    float* Sh = Sp + B * D;              // [B, D]
    float* H  = Sh + B * D;              // [B, D]

    // zero the atomic-accumulated S buffers (ws is poisoned each call)
    hipMemsetAsync(d_ws, 0, (size_t)2 * B * D * sizeof(float), stream);

    dim3 g1(LP / CH + LH / CH, B);       // (20, 64)
    gather_sum_kernel<<<g1, 512, 0, stream>>>(inputs_pre, inputs_hyp, emb, Sp, Sh);

    dim3 g2(D / 64, B / 4);              // (8, 16)
    mlp1_kernel<<<g2, 256, 0, stream>>>(Sp, Sh, W1, b1, H);

    mlp2_kernel<<<B, 256, 0, stream>>>(H, W2, b2, out);
}